// Round 1
// 104.351 us; speedup vs baseline: 1.0488x; 1.0488x over previous
//
#include <hip/hip_runtime.h>

// Problem constants
#define B_  16
#define T_  256
#define K_  128
#define DK_ 256
#define U_  128
#define TT_ 4      // timesteps per attn block (grid = 16*64 = 1024 -> 4 blocks/CU)

#define SCALE_ 2.8853900817779268f  // 2*log2(e): exp(2x) = exp2(SCALE_*x)

// Static device scratch. Both now hold EXP2 of the scaled pre-activation:
//   g_E2[m][u]  = exp2(SCALE_*(enc@W1+b1)),  m in [0, B*T)
//   g_Km2[n][u] = exp2(SCALE_*(knw@W2+b2)),  n in [0, B*K)
// so attn phase 1 uses exp2(e+k) = exp2(e)*exp2(k): per-term cost drops from
// {add, exp2, add, rcp, fma} = 3 VALU + 2 trans to {fma, rcp, fma} = 2 VALU +
// 1 trans. Overflow/underflow of the product are graceful (rcp(inf)=0 and
// rcp(1)=1 are the exact sigmoid limits).
__device__ float g_E2[B_ * T_ * U_];
__device__ float g_Km2[B_ * K_ * U_];

// ---------------------------------------------------------------------------
// Fused GEMMs: blocks [0,256) -> E (4096 rows of enc@W1+b1),
//              blocks [256,384) -> Km (2048 rows of knw@W2+b2).
// 16 rows/block, 2 rows/thread: 32 fma per 4 global float4 loads.
// (R4's 8-row variant doubled W re-reads per output and regressed; 16 rows
//  is the measured sweet spot.)
// Epilogue applies exp2 (8 trans per thread -- negligible here, removes one
// exp2 per TERM from the 67M-term attn phase 1).
// ---------------------------------------------------------------------------
__global__ __launch_bounds__(256) void gemm_both(const float* __restrict__ enc,
                                                 const float* __restrict__ W1,
                                                 const float* __restrict__ b1,
                                                 const float* __restrict__ knw,
                                                 const float* __restrict__ W2,
                                                 const float* __restrict__ b2) {
    __shared__ float Xs[16][256];   // 16 KB

    const int blk  = blockIdx.x;
    const bool isE = blk < 256;
    const float* __restrict__ X    = isE ? enc : knw;
    const float* __restrict__ W    = isE ? W1 : W2;
    const float* __restrict__ bias = isE ? b1 : b2;
    float* __restrict__ Y          = isE ? g_E2 : g_Km2;
    const int row0 = (isE ? blk : blk - 256) * 16;
    const int tid  = threadIdx.x;

    // Stage 16 rows x 256 floats = 1024 float4, 4 per thread, coalesced.
#pragma unroll
    for (int j = 0; j < 4; j++) {
        const int i  = tid + j * 256;
        const int rr = i >> 6, cc = i & 63;
        *(float4*)&Xs[rr][cc * 4] =
            *(const float4*)&X[(row0 + rr) * 256 + cc * 4];
    }
    __syncthreads();

    const int uc = tid & 31;          // u4 = 4*uc
    const int rp = (tid >> 5) * 2;    // rows rp, rp+1
    float4 a0 = {0.f, 0.f, 0.f, 0.f};
    float4 a1 = {0.f, 0.f, 0.f, 0.f};

    for (int d = 0; d < 256; d += 4) {
        const float4 xa = *(const float4*)&Xs[rp][d];       // broadcast
        const float4 xb = *(const float4*)&Xs[rp + 1][d];   // broadcast
        const float* wp = &W[d * 128 + uc * 4];
        const float4 w0 = *(const float4*)(wp);
        const float4 w1 = *(const float4*)(wp + 128);
        const float4 w2 = *(const float4*)(wp + 256);
        const float4 w3 = *(const float4*)(wp + 384);
        a0.x = fmaf(xa.x, w0.x, a0.x); a0.y = fmaf(xa.x, w0.y, a0.y);
        a0.z = fmaf(xa.x, w0.z, a0.z); a0.w = fmaf(xa.x, w0.w, a0.w);
        a0.x = fmaf(xa.y, w1.x, a0.x); a0.y = fmaf(xa.y, w1.y, a0.y);
        a0.z = fmaf(xa.y, w1.z, a0.z); a0.w = fmaf(xa.y, w1.w, a0.w);
        a0.x = fmaf(xa.z, w2.x, a0.x); a0.y = fmaf(xa.z, w2.y, a0.y);
        a0.z = fmaf(xa.z, w2.z, a0.z); a0.w = fmaf(xa.z, w2.w, a0.w);
        a0.x = fmaf(xa.w, w3.x, a0.x); a0.y = fmaf(xa.w, w3.y, a0.y);
        a0.z = fmaf(xa.w, w3.z, a0.z); a0.w = fmaf(xa.w, w3.w, a0.w);
        a1.x = fmaf(xb.x, w0.x, a1.x); a1.y = fmaf(xb.x, w0.y, a1.y);
        a1.z = fmaf(xb.x, w0.z, a1.z); a1.w = fmaf(xb.x, w0.w, a1.w);
        a1.x = fmaf(xb.y, w1.x, a1.x); a1.y = fmaf(xb.y, w1.y, a1.y);
        a1.z = fmaf(xb.y, w1.z, a1.z); a1.w = fmaf(xb.y, w1.w, a1.w);
        a1.x = fmaf(xb.z, w2.x, a1.x); a1.y = fmaf(xb.z, w2.y, a1.y);
        a1.z = fmaf(xb.z, w2.z, a1.z); a1.w = fmaf(xb.z, w2.w, a1.w);
        a1.x = fmaf(xb.w, w3.x, a1.x); a1.y = fmaf(xb.w, w3.y, a1.y);
        a1.z = fmaf(xb.w, w3.z, a1.z); a1.w = fmaf(xb.w, w3.w, a1.w);
    }

    const float4 b4 = *(const float4*)&bias[uc * 4];
    float4 o0, o1;
    o0.x = __builtin_amdgcn_exp2f(SCALE_ * (a0.x + b4.x));
    o0.y = __builtin_amdgcn_exp2f(SCALE_ * (a0.y + b4.y));
    o0.z = __builtin_amdgcn_exp2f(SCALE_ * (a0.z + b4.z));
    o0.w = __builtin_amdgcn_exp2f(SCALE_ * (a0.w + b4.w));
    o1.x = __builtin_amdgcn_exp2f(SCALE_ * (a1.x + b4.x));
    o1.y = __builtin_amdgcn_exp2f(SCALE_ * (a1.y + b4.y));
    o1.z = __builtin_amdgcn_exp2f(SCALE_ * (a1.z + b4.z));
    o1.w = __builtin_amdgcn_exp2f(SCALE_ * (a1.w + b4.w));
    *(float4*)&Y[(row0 + rp) * 128 + uc * 4]     = o0;
    *(float4*)&Y[(row0 + rp + 1) * 128 + uc * 4] = o1;
}

// ---------------------------------------------------------------------------
// Fused scores -> softmax -> context. One block per (b, tile of 4 t's).
// score_k = const - sum_u 2V[u]/(1+exp2(e'+k')); consts cancel in softmax
// over K. With exp2 precomputed in the GEMM epilogue, the per-term body is
// r = rcp(fma(ee, ek, 1)); na += v*r  -- 2 VALU + 1 trans (was 3 VALU +
// 2 trans). Prior session: issue-slot bound ("quad-rcp neutral; fewer issue
// slots wins"), so the 5->3 slot cut is the lever. No XCD swizzle (R4's
// pinning regressed). 4 barriers; softmax parallel across 4 waves.
// ---------------------------------------------------------------------------
__global__ __launch_bounds__(256, 4) void attn_ctx(const float* __restrict__ knw,
                                                   const float* __restrict__ V,
                                                   float* __restrict__ out) {
    __shared__ float sm[4][TT_][256];   // 16 KB: phase1 pA/V2s, phase2 part2
    __shared__ float E2s[TT_][U_];      // 2 KB (holds exp2 values now)
    __shared__ float attn[TT_][K_];     // 2 KB

    float* const pA  = &sm[0][0][0];    // [TT_][256] score partials
    float* const V2s = &sm[1][0][0];    // 128 floats = 2*V

    const int tid  = threadIdx.x;
    const int blk  = blockIdx.x;
    const int b    = blk >> 6;          // 64 t-tiles per batch
    const int t0   = (blk & 63) * TT_;
    const int lane = tid & 63;
    const int wave = tid >> 6;

    if (tid < 128) V2s[tid] = 2.0f * V[tid];
    if (tid < 128) {                    // stage E2 rows (4 x 128)
        const int ti = tid >> 5, uc = tid & 31;
        *(float4*)&E2s[ti][uc * 4] =
            *(const float4*)&g_E2[(b * T_ + t0 + ti) * U_ + uc * 4];
    }

    // Thread owns (k, half-of-U): 64 Km2 values in VGPRs, reused over 4 t's.
    const int k_idx = tid & 127;
    const int half  = tid >> 7;
    float4 km[16];
    {
        const float* kp = &g_Km2[(b * K_ + k_idx) * U_ + half * 64];
#pragma unroll
        for (int c = 0; c < 16; c++) km[c] = *(const float4*)&kp[c * 4];
    }
    __syncthreads();

    // ---- Phase 1: na[t] = sum_{u in half} 2V[u] * rcp(1 + ee*ek) ----
    // All E2s/V2s reads are wave-uniform addresses -> LDS broadcast, free.
    // inf/0 products saturate to the exact sigmoid limits (rcp(inf)=0, r=1).
    {
        float na[TT_] = {0.f, 0.f, 0.f, 0.f};
#pragma unroll
        for (int c = 0; c < 16; c++) {
            const float4 v4 = *(const float4*)&V2s[half * 64 + c * 4];
#pragma unroll
            for (int t = 0; t < TT_; t++) {
                const float4 e4 = *(const float4*)&E2s[t][half * 64 + c * 4];
                float r;
                r = __builtin_amdgcn_rcpf(fmaf(e4.x, km[c].x, 1.0f));
                na[t] = fmaf(v4.x, r, na[t]);
                r = __builtin_amdgcn_rcpf(fmaf(e4.y, km[c].y, 1.0f));
                na[t] = fmaf(v4.y, r, na[t]);
                r = __builtin_amdgcn_rcpf(fmaf(e4.z, km[c].z, 1.0f));
                na[t] = fmaf(v4.z, r, na[t]);
                r = __builtin_amdgcn_rcpf(fmaf(e4.w, km[c].w, 1.0f));
                na[t] = fmaf(v4.w, r, na[t]);
            }
        }
#pragma unroll
        for (int t = 0; t < TT_; t++) pA[t * 256 + tid] = na[t];
    }
    __syncthreads();

    // ---- Softmax over K=128: wave w owns timestep w ----
    {
        const int t = wave;
        const float* p = &pA[t * 256];
        float s0 = -(p[lane] + p[128 + lane]);
        float s1 = -(p[64 + lane] + p[192 + lane]);
        float m = fmaxf(s0, s1);
#pragma unroll
        for (int off = 32; off >= 1; off >>= 1)
            m = fmaxf(m, __shfl_xor(m, off));
        const float e0 = __builtin_amdgcn_exp2f(1.4426950408889634f * (s0 - m));
        const float e1 = __builtin_amdgcn_exp2f(1.4426950408889634f * (s1 - m));
        float ss = e0 + e1;
#pragma unroll
        for (int off = 32; off >= 1; off >>= 1)
            ss += __shfl_xor(ss, off);
        const float rinv = __builtin_amdgcn_rcpf(ss);
        attn[t][lane]      = e0 * rinv;
        attn[t][64 + lane] = e1 * rinv;
    }
    __syncthreads();

    // ---- Phase 2: context[ti][d] = sum_k attn[ti][k]*knw[b][k][d] ----
    // Wave kg covers k in [32kg, 32kg+32); lane covers d4 = 4*lane.
    {
        const int kg = wave, dq = lane;
        float4 acc[TT_];
#pragma unroll
        for (int ti = 0; ti < TT_; ti++) acc[ti] = make_float4(0.f, 0.f, 0.f, 0.f);

        const float* kp = &knw[(b * K_ + kg * 32) * DK_ + dq * 4];
#pragma unroll 4
        for (int ki = 0; ki < 32; ki++) {
            const float4 kn = *(const float4*)&kp[ki * DK_];
#pragma unroll
            for (int ti = 0; ti < TT_; ti++) {
                const float a = attn[ti][kg * 32 + ki];   // LDS broadcast
                acc[ti].x = fmaf(a, kn.x, acc[ti].x);
                acc[ti].y = fmaf(a, kn.y, acc[ti].y);
                acc[ti].z = fmaf(a, kn.z, acc[ti].z);
                acc[ti].w = fmaf(a, kn.w, acc[ti].w);
            }
        }
#pragma unroll
        for (int ti = 0; ti < TT_; ti++)
            *(float4*)&sm[kg][ti][dq * 4] = acc[ti];
    }
    __syncthreads();

    // Cross-wave K reduction + coalesced float4 store (4 rows x 256)
    {
        const int ti = tid >> 6, dd = tid & 63;
        const float4 s0 = *(const float4*)&sm[0][ti][dd * 4];
        const float4 s1 = *(const float4*)&sm[1][ti][dd * 4];
        const float4 s2 = *(const float4*)&sm[2][ti][dd * 4];
        const float4 s3 = *(const float4*)&sm[3][ti][dd * 4];
        float4 o;
        o.x = s0.x + s1.x + s2.x + s3.x;
        o.y = s0.y + s1.y + s2.y + s3.y;
        o.z = s0.z + s1.z + s2.z + s3.z;
        o.w = s0.w + s1.w + s2.w + s3.w;
        *(float4*)&out[(b * T_ + t0 + ti) * DK_ + dd * 4] = o;
    }
}

// ---------------------------------------------------------------------------
extern "C" void kernel_launch(void* const* d_in, const int* in_sizes, int n_in,
                              void* d_out, int out_size, void* d_ws,
                              size_t ws_size, hipStream_t stream) {
    (void)in_sizes; (void)n_in; (void)d_ws; (void)ws_size; (void)out_size;
    const float* knw = (const float*)d_in[0];  // [B,K,DK]
    const float* enc = (const float*)d_in[1];  // [B,T,DE]
    const float* W1  = (const float*)d_in[2];  // [DE,U]
    const float* b1  = (const float*)d_in[3];  // [U]
    const float* W2  = (const float*)d_in[4];  // [DK,U]
    const float* b2  = (const float*)d_in[5];  // [U]
    const float* V   = (const float*)d_in[6];  // [U,1]
    // d_in[7] = bV: constant over K, cancels in softmax -> unused.
    float* out = (float*)d_out;

    gemm_both<<<384, 256, 0, stream>>>(enc, W1, b1, knw, W2, b2);
    attn_ctx<<<B_ * (T_ / TT_), 256, 0, stream>>>(knw, V, out);
}

// Round 3
// 102.287 us; speedup vs baseline: 1.0700x; 1.0202x over previous
//
#include <hip/hip_runtime.h>

// Problem constants
#define B_  16
#define T_  256
#define K_  128
#define DK_ 256
#define U_  128
#define TT_ 4      // timesteps per attn block (grid = 16*64 = 1024 -> 4 blocks/CU)

#define SCALE_ 2.8853900817779268f  // 2*log2(e): exp(2x) = exp2(SCALE_*x)

// Km2 = exp2(SCALE_*(knw@W2+b2)) -- the only cross-kernel intermediate.
// (E2 is block-local in attn_ctx now; g_E2 and its round-trip are gone.
//  R2's cooperative single-kernel attempt never launched under graph
//  capture -> cross-block dependency stays as two stream-ordered kernels.)
__device__ float g_Km2[B_ * K_ * U_];

// ---------------------------------------------------------------------------
// Km-only GEMM: 128 blocks x 256 threads; block = 16 rows of the flattened
// [B*K]=2048 knowledge rows. W2 is read ~once per block (d-split across
// threads + LDS partial reduce): ~17 MB L2 traffic total, vs 134 MB for the
// old row-pair structure (which was L2-bound at ~8 us regardless of block
// partition -- W-passes/blocks ratio was invariant). Now ALU-bound, ~3 us.
// ---------------------------------------------------------------------------
__global__ __launch_bounds__(256) void gemm_km(const float* __restrict__ knw,
                                               const float* __restrict__ W2,
                                               const float* __restrict__ b2) {
    __shared__ float Xs[16][256];       // 16 KB staged rows
    __shared__ float part[4][16][128];  // 32 KB dq-partials

    const int tid  = threadIdx.x;
    const int row0 = blockIdx.x * 16;   // flat row: b = row>>7, k = row&127

    // Stage 16 rows x 256 floats, coalesced float4.
#pragma unroll
    for (int j = 0; j < 4; j++) {
        const int i  = tid + j * 256;
        const int rr = i >> 6, cc = i & 63;
        *(float4*)&Xs[rr][cc * 4] =
            *(const float4*)&knw[(row0 + rr) * 256 + cc * 4];
    }
    __syncthreads();

    // thread = (u4=4*(tid&31), dq=(tid>>5)&3, rh=tid>>7): 8 rows x 4 u x 64 d
    {
        const int uc = tid & 31;
        const int dq = (tid >> 5) & 3;
        const int rh = tid >> 7;
        float4 acc[8];
#pragma unroll
        for (int r = 0; r < 8; r++) acc[r] = make_float4(0.f, 0.f, 0.f, 0.f);
#pragma unroll 8
        for (int j = 0; j < 64; j++) {
            const int d = dq * 64 + j;
            const float4 w = *(const float4*)&W2[d * U_ + uc * 4];
#pragma unroll
            for (int r = 0; r < 8; r++) {
                const float x = Xs[rh * 8 + r][d];   // LDS broadcast
                acc[r].x = fmaf(x, w.x, acc[r].x);
                acc[r].y = fmaf(x, w.y, acc[r].y);
                acc[r].z = fmaf(x, w.z, acc[r].z);
                acc[r].w = fmaf(x, w.w, acc[r].w);
            }
        }
#pragma unroll
        for (int r = 0; r < 8; r++)
            *(float4*)&part[dq][rh * 8 + r][uc * 4] = acc[r];
    }
    __syncthreads();

    // Reduce 4 dq-partials: 2048 outputs / 256 threads = 8 each.
#pragma unroll
    for (int i = 0; i < 8; i++) {
        const int idx = tid + i * 256;
        const int r = idx >> 7, u = idx & 127;
        float s = b2[u];
#pragma unroll
        for (int dq = 0; dq < 4; dq++) s += part[dq][r][u];
        g_Km2[(row0 + r) * U_ + u] = __builtin_amdgcn_exp2f(SCALE_ * s);
    }
}

// ---------------------------------------------------------------------------
// Fused E-gemm -> scores -> softmax -> context. One block per (b, 4 t's).
// Prologue computes this block's own 4 rows of exp2(SCALE*(enc@W1+b1)) into
// LDS (consumed only here -> no global round-trip; W1 read once per block =
// 134 MB L2 vs 268 MB in the old standalone gemm). Then the R1-proven
// pipeline: phase1 r=rcp(fma(ee,ek,1)), softmax over K, context.
// ---------------------------------------------------------------------------
__global__ __launch_bounds__(256, 4) void attn_ctx(const float* __restrict__ knw,
                                                   const float* __restrict__ enc,
                                                   const float* __restrict__ W1,
                                                   const float* __restrict__ b1,
                                                   const float* __restrict__ V,
                                                   float* __restrict__ out) {
    __shared__ float sm[4][TT_][256];   // 16 KB: E-partials / pA / ctx parts
    __shared__ float encs[TT_][256];    // 4 KB staged enc rows
    __shared__ float E2s[TT_][U_];      // 2 KB exp2 of own E rows
    __shared__ float attn[TT_][K_];     // 2 KB
    __shared__ float V2s[U_];           // 0.5 KB  2*V
    float* const smf = &sm[0][0][0];    // 4096 floats, multi-use

    const int tid  = threadIdx.x;
    const int blk  = blockIdx.x;
    const int b    = blk >> 6;          // 64 t-tiles per batch
    const int t0   = (blk & 63) * TT_;
    const int lane = tid & 63;
    const int wave = tid >> 6;

    // ---- A0: stage enc (4 rows x 256) + V ----
    {
        const int rr = tid >> 6, cc = tid & 63;
        *(float4*)&encs[rr][cc * 4] =
            *(const float4*)&enc[(b * T_ + t0 + rr) * 256 + cc * 4];
        if (tid < 128) V2s[tid] = 2.0f * V[tid];
    }
    __syncthreads();

    // ---- A1: E partial dots. thread = (u4=4*(tid&31), dq=tid>>5). ----
    // W1 read once per block, coalesced float4 (2x512B segments per wave).
    {
        const int uc = tid & 31;
        const int dq = tid >> 5;        // d in [dq*32, dq*32+32)
        float4 a0 = {0,0,0,0}, a1 = {0,0,0,0}, a2 = {0,0,0,0}, a3 = {0,0,0,0};
#pragma unroll 8
        for (int j = 0; j < 32; j++) {
            const int d = dq * 32 + j;
            const float4 w = *(const float4*)&W1[d * U_ + uc * 4];
            const float e0 = encs[0][d], e1 = encs[1][d];
            const float e2 = encs[2][d], e3 = encs[3][d];
            a0.x = fmaf(e0, w.x, a0.x); a0.y = fmaf(e0, w.y, a0.y);
            a0.z = fmaf(e0, w.z, a0.z); a0.w = fmaf(e0, w.w, a0.w);
            a1.x = fmaf(e1, w.x, a1.x); a1.y = fmaf(e1, w.y, a1.y);
            a1.z = fmaf(e1, w.z, a1.z); a1.w = fmaf(e1, w.w, a1.w);
            a2.x = fmaf(e2, w.x, a2.x); a2.y = fmaf(e2, w.y, a2.y);
            a2.z = fmaf(e2, w.z, a2.z); a2.w = fmaf(e2, w.w, a2.w);
            a3.x = fmaf(e3, w.x, a3.x); a3.y = fmaf(e3, w.y, a3.y);
            a3.z = fmaf(e3, w.z, a3.z); a3.w = fmaf(e3, w.w, a3.w);
        }
        *(float4*)&smf[(dq * 4 + 0) * 128 + uc * 4] = a0;
        *(float4*)&smf[(dq * 4 + 1) * 128 + uc * 4] = a1;
        *(float4*)&smf[(dq * 4 + 2) * 128 + uc * 4] = a2;
        *(float4*)&smf[(dq * 4 + 3) * 128 + uc * 4] = a3;
    }
    __syncthreads();

    // km loads issued here (independent of LDS) -> overlap the A2 reduce.
    const int k_idx = tid & 127;
    const int half  = tid >> 7;
    float4 km[16];
    {
        const float* kp = &g_Km2[(b * K_ + k_idx) * U_ + half * 64];
#pragma unroll
        for (int c = 0; c < 16; c++) km[c] = *(const float4*)&kp[c * 4];
    }

    // ---- A2: reduce 8 dq-partials + bias + exp2 -> E2s ----
    {
        const int ti = tid >> 6, uu = tid & 63;
#pragma unroll
        for (int h = 0; h < 128; h += 64) {
            float s = b1[uu + h];
#pragma unroll
            for (int dq = 0; dq < 8; dq++)
                s += smf[(dq * 4 + ti) * 128 + uu + h];
            E2s[ti][uu + h] = __builtin_amdgcn_exp2f(SCALE_ * s);
        }
    }
    __syncthreads();

    float* const pA = smf;              // [TT_][256] score partials

    // ---- Phase 1: na[t] = sum_{u in half} 2V[u] * rcp(1 + ee*ek) ----
    // E2s/V2s reads are wave-uniform -> LDS broadcast. inf/0 products
    // saturate to the exact sigmoid limits (rcp(inf)=0, r=1).
    {
        float na[TT_] = {0.f, 0.f, 0.f, 0.f};
#pragma unroll
        for (int c = 0; c < 16; c++) {
            const float4 v4 = *(const float4*)&V2s[half * 64 + c * 4];
#pragma unroll
            for (int t = 0; t < TT_; t++) {
                const float4 e4 = *(const float4*)&E2s[t][half * 64 + c * 4];
                float r;
                r = __builtin_amdgcn_rcpf(fmaf(e4.x, km[c].x, 1.0f));
                na[t] = fmaf(v4.x, r, na[t]);
                r = __builtin_amdgcn_rcpf(fmaf(e4.y, km[c].y, 1.0f));
                na[t] = fmaf(v4.y, r, na[t]);
                r = __builtin_amdgcn_rcpf(fmaf(e4.z, km[c].z, 1.0f));
                na[t] = fmaf(v4.z, r, na[t]);
                r = __builtin_amdgcn_rcpf(fmaf(e4.w, km[c].w, 1.0f));
                na[t] = fmaf(v4.w, r, na[t]);
            }
        }
#pragma unroll
        for (int t = 0; t < TT_; t++) pA[t * 256 + tid] = na[t];
    }
    __syncthreads();

    // ---- Softmax over K=128: wave w owns timestep w ----
    {
        const int t = wave;
        const float* p = &pA[t * 256];
        float s0 = -(p[lane] + p[128 + lane]);
        float s1 = -(p[64 + lane] + p[192 + lane]);
        float m = fmaxf(s0, s1);
#pragma unroll
        for (int off = 32; off >= 1; off >>= 1)
            m = fmaxf(m, __shfl_xor(m, off));
        const float e0 = __builtin_amdgcn_exp2f(1.4426950408889634f * (s0 - m));
        const float e1 = __builtin_amdgcn_exp2f(1.4426950408889634f * (s1 - m));
        float ss = e0 + e1;
#pragma unroll
        for (int off = 32; off >= 1; off >>= 1)
            ss += __shfl_xor(ss, off);
        const float rinv = __builtin_amdgcn_rcpf(ss);
        attn[t][lane]      = e0 * rinv;
        attn[t][64 + lane] = e1 * rinv;
    }
    __syncthreads();

    // ---- Phase 2: context[ti][d] = sum_k attn[ti][k]*knw[b][k][d] ----
    // Wave kg covers k in [32kg, 32kg+32); lane covers d4 = 4*lane.
    {
        const int kg = wave, dq = lane;
        float4 acc[TT_];
#pragma unroll
        for (int ti = 0; ti < TT_; ti++) acc[ti] = make_float4(0.f, 0.f, 0.f, 0.f);

        const float* kp = &knw[(b * K_ + kg * 32) * DK_ + dq * 4];
#pragma unroll 4
        for (int ki = 0; ki < 32; ki++) {
            const float4 kn = *(const float4*)&kp[ki * DK_];
#pragma unroll
            for (int ti = 0; ti < TT_; ti++) {
                const float a = attn[ti][kg * 32 + ki];   // LDS broadcast
                acc[ti].x = fmaf(a, kn.x, acc[ti].x);
                acc[ti].y = fmaf(a, kn.y, acc[ti].y);
                acc[ti].z = fmaf(a, kn.z, acc[ti].z);
                acc[ti].w = fmaf(a, kn.w, acc[ti].w);
            }
        }
#pragma unroll
        for (int ti = 0; ti < TT_; ti++)
            *(float4*)&smf[(kg * TT_ + ti) * 256 + dq * 4] = acc[ti];
    }
    __syncthreads();

    // Cross-wave K reduction + coalesced float4 store (4 rows x 256)
    {
        const int ti = tid >> 6, dd = tid & 63;
        const float4 s0 = *(const float4*)&smf[(0 * TT_ + ti) * 256 + dd * 4];
        const float4 s1 = *(const float4*)&smf[(1 * TT_ + ti) * 256 + dd * 4];
        const float4 s2 = *(const float4*)&smf[(2 * TT_ + ti) * 256 + dd * 4];
        const float4 s3 = *(const float4*)&smf[(3 * TT_ + ti) * 256 + dd * 4];
        float4 o;
        o.x = s0.x + s1.x + s2.x + s3.x;
        o.y = s0.y + s1.y + s2.y + s3.y;
        o.z = s0.z + s1.z + s2.z + s3.z;
        o.w = s0.w + s1.w + s2.w + s3.w;
        *(float4*)&out[(b * T_ + t0 + ti) * DK_ + dd * 4] = o;
    }
}

// ---------------------------------------------------------------------------
extern "C" void kernel_launch(void* const* d_in, const int* in_sizes, int n_in,
                              void* d_out, int out_size, void* d_ws,
                              size_t ws_size, hipStream_t stream) {
    (void)in_sizes; (void)n_in; (void)d_ws; (void)ws_size; (void)out_size;
    const float* knw = (const float*)d_in[0];  // [B,K,DK]
    const float* enc = (const float*)d_in[1];  // [B,T,DE]
    const float* W1  = (const float*)d_in[2];  // [DE,U]
    const float* b1  = (const float*)d_in[3];  // [U]
    const float* W2  = (const float*)d_in[4];  // [DK,U]
    const float* b2  = (const float*)d_in[5];  // [U]
    const float* V   = (const float*)d_in[6];  // [U,1]
    // d_in[7] = bV: constant over K, cancels in softmax -> unused.
    float* out = (float*)d_out;

    gemm_km<<<128, 256, 0, stream>>>(knw, W2, b2);
    attn_ctx<<<B_ * (T_ / TT_), 256, 0, stream>>>(knw, enc, W1, b1, V, out);
}